// Round 5
// baseline (883.094 us; speedup 1.0000x reference)
//
#include <hip/hip_runtime.h>
#include <math.h>

#define BS   2048
#define DIM  2048
#define NE   64
#define NF   512
#define TOPK 8

typedef __attribute__((ext_vector_type(8))) short bf16x8;
typedef __attribute__((ext_vector_type(4))) float f32x4;

// pack 2 f32 -> 2 bf16 (RNE), lo in [15:0]
__device__ __forceinline__ unsigned cvt2(float lo, float hi) {
    unsigned r;
    asm("v_cvt_pk_bf16_f32 %0, %1, %2" : "=v"(r) : "v"(lo), "v"(hi));
    return r;
}
__device__ __forceinline__ unsigned short f2bf(float f) {
    unsigned r = cvt2(f, 0.f);
    return (unsigned short)(r & 0xFFFF);
}

// swizzled LDS addressing: 64-col bf16 rows (128 B), XOR bits 4-6 with row&7
#define SWZ(r, b) (((((r) << 7) + (b)) ^ (((r) & 7) << 4)))

// ---------------- zero out + counters ----------------
__global__ __launch_bounds__(256) void zero_kernel(float* __restrict__ out, int* __restrict__ count)
{
    const size_t idx = (size_t)blockIdx.x * blockDim.x + threadIdx.x;
    const size_t tot = (size_t)BS * DIM;
    for (size_t i = idx * 4; i < tot; i += (size_t)gridDim.x * blockDim.x * 4) {
        *(float4*)&out[i] = make_float4(0.f, 0.f, 0.f, 0.f);
    }
    if (idx < NE) count[idx] = 0;
}

// ---------------- router: 4 tokens/block, wave-parallel top-8 ----------------
__global__ __launch_bounds__(256) void router_kernel(
    const float* __restrict__ x, const float* __restrict__ gate_w,
    const int* __restrict__ token_mod, const int* __restrict__ expert_mod,
    int* __restrict__ count, int* __restrict__ list_token, float* __restrict__ list_w)
{
    __shared__ float xs[4 * DIM];
    __shared__ float pr[4][NE];
    const int t0  = blockIdx.x * 4;
    const int tid = threadIdx.x;
    const int lane = tid & 63, wave = tid >> 6;

    float4* xs4 = (float4*)xs;
    const float4* xr = (const float4*)(x + (size_t)t0 * DIM);
    for (int i = tid; i < 4 * (DIM / 4); i += 256) xs4[i] = xr[i];
    __syncthreads();

    for (int j = 0; j < 16; ++j) {
        const int e = wave * 16 + j;
        const float4* gw = (const float4*)(gate_w + (size_t)e * DIM);
        float s0 = 0.f, s1 = 0.f, s2 = 0.f, s3 = 0.f;
        for (int i = lane; i < DIM / 4; i += 64) {
            const float4 g  = gw[i];
            const float4 v0 = xs4[0 * 512 + i];
            const float4 v1 = xs4[1 * 512 + i];
            const float4 v2 = xs4[2 * 512 + i];
            const float4 v3 = xs4[3 * 512 + i];
            s0 += v0.x * g.x + v0.y * g.y + v0.z * g.z + v0.w * g.w;
            s1 += v1.x * g.x + v1.y * g.y + v1.z * g.z + v1.w * g.w;
            s2 += v2.x * g.x + v2.y * g.y + v2.z * g.z + v2.w * g.w;
            s3 += v3.x * g.x + v3.y * g.y + v3.z * g.z + v3.w * g.w;
        }
        #pragma unroll
        for (int off = 32; off > 0; off >>= 1) {
            s0 += __shfl_xor(s0, off, 64);
            s1 += __shfl_xor(s1, off, 64);
            s2 += __shfl_xor(s2, off, 64);
            s3 += __shfl_xor(s3, off, 64);
        }
        if (lane == 0) {
            pr[0][e] = s0; pr[1][e] = s1; pr[2][e] = s2; pr[3][e] = s3;
        }
    }
    __syncthreads();

    {
        const int t  = t0 + wave;
        const int tm = token_mod[t];
        const int em = expert_mod[lane];
        float p = pr[wave][lane];
        if (tm * em == -1) p = -INFINITY;
        float m0 = p;
        #pragma unroll
        for (int off = 32; off > 0; off >>= 1) m0 = fmaxf(m0, __shfl_xor(m0, off, 64));
        p = __expf(p - m0);                  // exp(-inf)=0; softmax denom cancels in renorm
        float s8 = 0.f, wsel = 0.f;
        int   esel = 0;
        #pragma unroll
        for (int k = 0; k < TOPK; ++k) {
            float m = p;
            #pragma unroll
            for (int off = 32; off > 0; off >>= 1) m = fmaxf(m, __shfl_xor(m, off, 64));
            const unsigned long long b = __ballot(p == m);
            const int bi = __ffsll((unsigned long long)b) - 1;   // lowest index on ties
            if (lane == bi) p = -1.f;
            if (lane == k) { esel = bi; wsel = m; }
            s8 += m;
        }
        const float inv = 1.f / s8;
        if (lane < TOPK) {
            const int pos = atomicAdd(&count[esel], 1);
            list_token[esel * BS + pos] = t;
            list_w[esel * BS + pos]     = wsel * inv;
        }
    }
}

// ---------------- tiny exclusive scan over 64 counts ----------------
__global__ void scan_kernel(const int* __restrict__ count, int* __restrict__ offsets)
{
    if (threadIdx.x == 0) {
        int s = 0;
        for (int e = 0; e < NE; ++e) { offsets[e] = s; s += count[e]; }
    }
}

// ---------------- gate/up MFMA GEMM (single-buffer LDS, reg dbuf) -> h (bf16) ----------------
// block: 64 tokens x 64 f, BK=64, 32 K-steps. 4 waves; wave = 32 tok x 32 f (gate+up).
// LDS: X 8KB | G 8KB | U 8KB = 24KB single buffer -> 4 blocks/CU.
#define GU_X   0
#define GU_G   8192
#define GU_U   16384

#define GU_COMPUTE()                                                                  \
    {                                                                                 \
        _Pragma("unroll")                                                             \
        for (int ks = 0; ks < 2; ++ks) {                                              \
            const int kb = (ks * 32 + (lane >> 4) * 8) * 2;                           \
            bf16x8 a[2], bg[2], bu[2];                                                \
            _Pragma("unroll")                                                         \
            for (int m = 0; m < 2; ++m)                                               \
                a[m] = *(const bf16x8*)&lds[GU_X + SWZ(wr * 32 + m * 16 + (lane & 15), kb)]; \
            _Pragma("unroll")                                                         \
            for (int nn = 0; nn < 2; ++nn) {                                          \
                const int r = wc * 32 + nn * 16 + (lane & 15);                        \
                bg[nn] = *(const bf16x8*)&lds[GU_G + SWZ(r, kb)];                     \
                bu[nn] = *(const bf16x8*)&lds[GU_U + SWZ(r, kb)];                     \
            }                                                                         \
            _Pragma("unroll")                                                         \
            for (int m = 0; m < 2; ++m)                                               \
                _Pragma("unroll")                                                     \
                for (int nn = 0; nn < 2; ++nn) {                                      \
                    accg[m][nn] = __builtin_amdgcn_mfma_f32_16x16x32_bf16(a[m], bg[nn], accg[m][nn], 0, 0, 0); \
                    accu[m][nn] = __builtin_amdgcn_mfma_f32_16x16x32_bf16(a[m], bu[nn], accu[m][nn], 0, 0, 0); \
                }                                                                     \
        }                                                                             \
    }

#define GU_WRITE()                                                                    \
    {                                                                                 \
        _Pragma("unroll")                                                             \
        for (int i = 0; i < 4; ++i) {                                                 \
            const int r = rr + i * 16;                                                \
            *(uint2*)&lds[GU_X + SWZ(r, c4 * 8)] = make_uint2(cvt2(lx[i].x, lx[i].y), cvt2(lx[i].z, lx[i].w)); \
            *(uint2*)&lds[GU_G + SWZ(r, c4 * 8)] = make_uint2(cvt2(lg[i].x, lg[i].y), cvt2(lg[i].z, lg[i].w)); \
            *(uint2*)&lds[GU_U + SWZ(r, c4 * 8)] = make_uint2(cvt2(lu[i].x, lu[i].y), cvt2(lu[i].z, lu[i].w)); \
        }                                                                             \
    }

__global__ __launch_bounds__(256, 4) void gateup_mfma(
    const float* __restrict__ x,
    const float* __restrict__ w_gate, const float* __restrict__ w_up,
    const int* __restrict__ count, const int* __restrict__ offsets,
    const int* __restrict__ list_token, const float* __restrict__ list_w,
    unsigned short* __restrict__ h)
{
    const int e  = blockIdx.z;
    const int n  = count[e];
    const int m0 = blockIdx.y * 64;
    if (m0 >= n) return;
    const int f0 = blockIdx.x * 64;
    const int mc = min(64, n - m0);

    __shared__ char  lds[24576];
    __shared__ int   toks[64];
    __shared__ float rws[64];

    const int tid = threadIdx.x;
    if (tid < 64) {
        const int idx = e * BS + m0 + (tid < mc ? tid : 0);
        toks[tid] = list_token[idx];
        rws[tid]  = (tid < mc) ? list_w[idx] : 0.f;
    }
    __syncthreads();

    const int lane = tid & 63, wave = tid >> 6;
    const int wr = wave >> 1, wc = wave & 1;
    const int rr = tid >> 4;          // 0..15 staging row base
    const int c4 = tid & 15;          // float4 col index (16 per row)

    const float* xrow[4];
    #pragma unroll
    for (int i = 0; i < 4; ++i) xrow[i] = x + (size_t)toks[rr + i * 16] * DIM + c4 * 4;
    const float* grow[4];
    const float* urow[4];
    #pragma unroll
    for (int i = 0; i < 4; ++i) {
        grow[i] = w_gate + (size_t)e * NF * DIM + (size_t)(f0 + rr + i * 16) * DIM + c4 * 4;
        urow[i] = w_up   + (size_t)e * NF * DIM + (size_t)(f0 + rr + i * 16) * DIM + c4 * 4;
    }

    f32x4 accg[2][2] = {};
    f32x4 accu[2][2] = {};
    float4 lx[4], lg[4], lu[4];

    // prologue: stage step 0
    #pragma unroll
    for (int i = 0; i < 4; ++i) {
        lx[i] = *(const float4*)(xrow[i]);
        lg[i] = *(const float4*)(grow[i]);
        lu[i] = *(const float4*)(urow[i]);
    }
    GU_WRITE();
    __syncthreads();

    for (int t = 0; t < DIM / 64 - 1; ++t) {
        const int doff = (t + 1) * 64;
        // issue next-step loads (in flight across compute)
        #pragma unroll
        for (int i = 0; i < 4; ++i) {
            lx[i] = *(const float4*)(xrow[i] + doff);
            lg[i] = *(const float4*)(grow[i] + doff);
            lu[i] = *(const float4*)(urow[i] + doff);
        }
        GU_COMPUTE();
        __syncthreads();        // everyone done reading lds
        GU_WRITE();
        __syncthreads();        // next tile visible
    }
    GU_COMPUTE();

    const int base = offsets[e] + m0;
    #pragma unroll
    for (int m = 0; m < 2; ++m) {
        #pragma unroll
        for (int j = 0; j < 4; ++j) {
            const int tl = wr * 32 + m * 16 + (lane >> 4) * 4 + j;
            if (tl < mc) {
                const float w = rws[tl];
                #pragma unroll
                for (int nn = 0; nn < 2; ++nn) {
                    const int fl = f0 + wc * 32 + nn * 16 + (lane & 15);
                    const float g  = accg[m][nn][j];
                    const float u  = accu[m][nn][j];
                    const float hv = w * u * (g / (1.f + __expf(-g)));
                    h[(size_t)(base + tl) * NF + fl] = f2bf(hv);
                }
            }
        }
    }
}

// ---------------- down MFMA GEMM (single-buffer LDS, reg dbuf) + atomic combine ----------------
// block: 64 slots x 128 d, BK=64 over F=512 (8 steps). 4 waves; wave = 32 x 64.
// LDS: H 8KB | W 16KB = 24KB single buffer -> 4 blocks/CU.
#define DK_H   0
#define DK_W   8192

#define DK_COMPUTE()                                                                  \
    {                                                                                 \
        _Pragma("unroll")                                                             \
        for (int ks = 0; ks < 2; ++ks) {                                              \
            const int kb = (ks * 32 + (lane >> 4) * 8) * 2;                           \
            bf16x8 a[2], b[4];                                                        \
            _Pragma("unroll")                                                         \
            for (int m = 0; m < 2; ++m)                                               \
                a[m] = *(const bf16x8*)&lds[DK_H + SWZ(wr * 32 + m * 16 + (lane & 15), kb)]; \
            _Pragma("unroll")                                                         \
            for (int nn = 0; nn < 4; ++nn)                                            \
                b[nn] = *(const bf16x8*)&lds[DK_W + SWZ(wc * 64 + nn * 16 + (lane & 15), kb)]; \
            _Pragma("unroll")                                                         \
            for (int m = 0; m < 2; ++m)                                               \
                _Pragma("unroll")                                                     \
                for (int nn = 0; nn < 4; ++nn)                                        \
                    acc[m][nn] = __builtin_amdgcn_mfma_f32_16x16x32_bf16(a[m], b[nn], acc[m][nn], 0, 0, 0); \
        }                                                                             \
    }

#define DK_WRITE()                                                                    \
    {                                                                                 \
        _Pragma("unroll")                                                             \
        for (int i = 0; i < 2; ++i)                                                   \
            *(uint4*)&lds[DK_H + SWZ(hr + i * 32, hc * 2)] = lh[i];                   \
        _Pragma("unroll")                                                             \
        for (int i = 0; i < 8; ++i)                                                   \
            *(uint2*)&lds[DK_W + SWZ(rr + i * 16, c4 * 8)] = make_uint2(cvt2(lw[i].x, lw[i].y), cvt2(lw[i].z, lw[i].w)); \
    }

__global__ __launch_bounds__(256, 4) void down_mfma(
    const float* __restrict__ w_down,
    const int* __restrict__ count, const int* __restrict__ offsets,
    const int* __restrict__ list_token,
    const unsigned short* __restrict__ h, float* __restrict__ out)
{
    const int e  = blockIdx.z;
    const int n  = count[e];
    const int m0 = blockIdx.y * 64;
    if (m0 >= n) return;
    const int d0 = blockIdx.x * 128;
    const int mc = min(64, n - m0);

    __shared__ char lds[24576];
    __shared__ int  toks[64];

    const int tid = threadIdx.x;
    if (tid < 64) toks[tid] = list_token[e * BS + m0 + (tid < mc ? tid : 0)];
    __syncthreads();

    const int lane = tid & 63, wave = tid >> 6;
    const int wr = wave >> 1, wc = wave & 1;
    const int rr = tid >> 4;          // 0..15 (W rows)
    const int c4 = tid & 15;          // float4 col
    const int hr = tid >> 3;          // 0..31 (H rows)
    const int hc = (tid & 7) * 8;     // bf16 col (8 per 16B)

    const float* wd  = w_down + (size_t)e * DIM * NF;
    const int   base = offsets[e] + m0;

    const unsigned short* hrow[2];
    #pragma unroll
    for (int i = 0; i < 2; ++i) {
        const int r  = hr + i * 32;
        const int rs = (r < mc ? r : 0);
        hrow[i] = h + (size_t)(base + rs) * NF + hc;
    }
    const float* wrow[8];
    #pragma unroll
    for (int i = 0; i < 8; ++i) wrow[i] = wd + (size_t)(d0 + rr + i * 16) * NF + c4 * 4;

    f32x4 acc[2][4] = {};
    uint4  lh[2];
    float4 lw[8];

    // prologue
    #pragma unroll
    for (int i = 0; i < 2; ++i) lh[i] = *(const uint4*)(hrow[i]);
    #pragma unroll
    for (int i = 0; i < 8; ++i) lw[i] = *(const float4*)(wrow[i]);
    DK_WRITE();
    __syncthreads();

    for (int t = 0; t < NF / 64 - 1; ++t) {
        const int foff = (t + 1) * 64;
        #pragma unroll
        for (int i = 0; i < 2; ++i) lh[i] = *(const uint4*)(hrow[i] + foff);
        #pragma unroll
        for (int i = 0; i < 8; ++i) lw[i] = *(const float4*)(wrow[i] + foff);
        DK_COMPUTE();
        __syncthreads();
        DK_WRITE();
        __syncthreads();
    }
    DK_COMPUTE();

    #pragma unroll
    for (int m = 0; m < 2; ++m)
        #pragma unroll
        for (int j = 0; j < 4; ++j) {
            const int sl = wr * 32 + m * 16 + (lane >> 4) * 4 + j;
            if (sl < mc) {
                float* orow = out + (size_t)toks[sl] * DIM + d0 + wc * 64 + (lane & 15);
                #pragma unroll
                for (int nn = 0; nn < 4; ++nn)
                    atomicAdd(&orow[nn * 16], acc[m][nn][j]);
            }
        }
}

extern "C" void kernel_launch(void* const* d_in, const int* in_sizes, int n_in,
                              void* d_out, int out_size, void* d_ws, size_t ws_size,
                              hipStream_t stream)
{
    const float* x          = (const float*)d_in[0];
    const float* gate_w     = (const float*)d_in[1];
    const float* w_gate     = (const float*)d_in[2];
    const float* w_up       = (const float*)d_in[3];
    const float* w_down     = (const float*)d_in[4];
    const int*   token_mod  = (const int*)d_in[5];
    const int*   expert_mod = (const int*)d_in[6];
    float* out = (float*)d_out;

    // ws layout: h bf16 (16384*512*2 = 16,777,216 B) | count | offsets | list_token | list_w
    char* ws = (char*)d_ws;
    unsigned short* h  = (unsigned short*)ws;
    int*   count      = (int*)(ws + 16777216);
    int*   offsets    = (int*)(ws + 16777216 + 256);
    int*   list_token = (int*)(ws + 16777216 + 512);
    float* list_w     = (float*)(ws + 16777216 + 512 + (size_t)NE * BS * 4);

    zero_kernel<<<2048, 256, 0, stream>>>(out, count);
    router_kernel<<<BS / 4, 256, 0, stream>>>(x, gate_w, token_mod, expert_mod,
                                              count, list_token, list_w);
    scan_kernel<<<1, 64, 0, stream>>>(count, offsets);

    dim3 g1(NF / 64, BS / 64, NE);     // (8, 32, 64)
    gateup_mfma<<<g1, 256, 0, stream>>>(x, w_gate, w_up, count, offsets,
                                        list_token, list_w, h);
    dim3 g2(DIM / 128, BS / 64, NE);   // (16, 32, 64)
    down_mfma<<<g2, 256, 0, stream>>>(w_down, count, offsets, list_token, h, out);
}

// Round 6
// 574.482 us; speedup vs baseline: 1.5372x; 1.5372x over previous
//
#include <hip/hip_runtime.h>
#include <math.h>

#define BS   2048
#define DIM  2048
#define NE   64
#define NF   512
#define TOPK 8

typedef __attribute__((ext_vector_type(8))) short bf16x8;
typedef __attribute__((ext_vector_type(4))) float f32x4;

// pack 2 f32 -> 2 bf16 (RNE), lo in [15:0]
__device__ __forceinline__ unsigned cvt2(float lo, float hi) {
    unsigned r;
    asm("v_cvt_pk_bf16_f32 %0, %1, %2" : "=v"(r) : "v"(lo), "v"(hi));
    return r;
}
__device__ __forceinline__ unsigned short f2bf(float f) {
    return (unsigned short)(cvt2(f, 0.f) & 0xFFFF);
}

// async global -> LDS, 16B per lane. LDS dest = wave-uniform base + lane*16.
__device__ __forceinline__ void gll16(const void* g, void* l) {
    __builtin_amdgcn_global_load_lds(
        (const __attribute__((address_space(1))) void*)g,
        (__attribute__((address_space(3))) void*)l, 16, 0, 0);
}

// fragment from fp32 LDS tile with 128-B rows, source-swizzled cb ^= row&7.
// returns 8 consecutive k-elements (cb0, cb0+1) converted to bf16.
__device__ __forceinline__ bf16x8 fragf32(const char* p, int row, int cb0) {
    const int sw = row & 7;
    const f32x4 lo = *(const f32x4*)(p + (row << 7) + ((cb0 ^ sw) << 4));
    const f32x4 hi = *(const f32x4*)(p + (row << 7) + (((cb0 + 1) ^ sw) << 4));
    union { bf16x8 v; unsigned u[4]; } r;
    r.u[0] = cvt2(lo[0], lo[1]);
    r.u[1] = cvt2(lo[2], lo[3]);
    r.u[2] = cvt2(hi[0], hi[1]);
    r.u[3] = cvt2(hi[2], hi[3]);
    return r.v;
}
// fragment from bf16 LDS tile with 64-B rows, source-swizzled cb ^= (row>>1)&3.
__device__ __forceinline__ bf16x8 fragbf16(const char* p, int row, int cb) {
    return *(const bf16x8*)(p + (row << 6) + ((cb ^ ((row >> 1) & 3)) << 4));
}

// ---------------- zero out + counters ----------------
__global__ __launch_bounds__(256) void zero_kernel(float* __restrict__ out, int* __restrict__ count)
{
    const size_t idx = (size_t)blockIdx.x * blockDim.x + threadIdx.x;
    const size_t tot = (size_t)BS * DIM;
    for (size_t i = idx * 4; i < tot; i += (size_t)gridDim.x * blockDim.x * 4) {
        *(float4*)&out[i] = make_float4(0.f, 0.f, 0.f, 0.f);
    }
    if (idx < NE) count[idx] = 0;
}

// ---------------- router: 4 tokens/block, wave-parallel top-8 ----------------
__global__ __launch_bounds__(256) void router_kernel(
    const float* __restrict__ x, const float* __restrict__ gate_w,
    const int* __restrict__ token_mod, const int* __restrict__ expert_mod,
    int* __restrict__ count, int* __restrict__ list_token, float* __restrict__ list_w)
{
    __shared__ float xs[4 * DIM];
    __shared__ float pr[4][NE];
    const int t0  = blockIdx.x * 4;
    const int tid = threadIdx.x;
    const int lane = tid & 63, wave = tid >> 6;

    float4* xs4 = (float4*)xs;
    const float4* xr = (const float4*)(x + (size_t)t0 * DIM);
    for (int i = tid; i < 4 * (DIM / 4); i += 256) xs4[i] = xr[i];
    __syncthreads();

    for (int j = 0; j < 16; ++j) {
        const int e = wave * 16 + j;
        const float4* gw = (const float4*)(gate_w + (size_t)e * DIM);
        float s0 = 0.f, s1 = 0.f, s2 = 0.f, s3 = 0.f;
        for (int i = lane; i < DIM / 4; i += 64) {
            const float4 g  = gw[i];
            const float4 v0 = xs4[0 * 512 + i];
            const float4 v1 = xs4[1 * 512 + i];
            const float4 v2 = xs4[2 * 512 + i];
            const float4 v3 = xs4[3 * 512 + i];
            s0 += v0.x * g.x + v0.y * g.y + v0.z * g.z + v0.w * g.w;
            s1 += v1.x * g.x + v1.y * g.y + v1.z * g.z + v1.w * g.w;
            s2 += v2.x * g.x + v2.y * g.y + v2.z * g.z + v2.w * g.w;
            s3 += v3.x * g.x + v3.y * g.y + v3.z * g.z + v3.w * g.w;
        }
        #pragma unroll
        for (int off = 32; off > 0; off >>= 1) {
            s0 += __shfl_xor(s0, off, 64);
            s1 += __shfl_xor(s1, off, 64);
            s2 += __shfl_xor(s2, off, 64);
            s3 += __shfl_xor(s3, off, 64);
        }
        if (lane == 0) {
            pr[0][e] = s0; pr[1][e] = s1; pr[2][e] = s2; pr[3][e] = s3;
        }
    }
    __syncthreads();

    {
        const int t  = t0 + wave;
        const int tm = token_mod[t];
        const int em = expert_mod[lane];
        float p = pr[wave][lane];
        if (tm * em == -1) p = -INFINITY;
        float m0 = p;
        #pragma unroll
        for (int off = 32; off > 0; off >>= 1) m0 = fmaxf(m0, __shfl_xor(m0, off, 64));
        p = __expf(p - m0);                  // exp(-inf)=0; softmax denom cancels in renorm
        float s8 = 0.f, wsel = 0.f;
        int   esel = 0;
        #pragma unroll
        for (int k = 0; k < TOPK; ++k) {
            float m = p;
            #pragma unroll
            for (int off = 32; off > 0; off >>= 1) m = fmaxf(m, __shfl_xor(m, off, 64));
            const unsigned long long b = __ballot(p == m);
            const int bi = __ffsll((unsigned long long)b) - 1;   // lowest index on ties
            if (lane == bi) p = -1.f;
            if (lane == k) { esel = bi; wsel = m; }
            s8 += m;
        }
        const float inv = 1.f / s8;
        if (lane < TOPK) {
            const int pos = atomicAdd(&count[esel], 1);
            list_token[esel * BS + pos] = t;
            list_w[esel * BS + pos]     = wsel * inv;
        }
    }
}

// ---------------- tiny exclusive scan over 64 counts ----------------
__global__ void scan_kernel(const int* __restrict__ count, int* __restrict__ offsets)
{
    if (threadIdx.x == 0) {
        int s = 0;
        for (int e = 0; e < NE; ++e) { offsets[e] = s; s += count[e]; }
    }
}

// ---------------- gate/up MFMA GEMM: async gll pipeline, BK=32, 64 steps ----------------
// block: 64 tok x 64 f. 4 waves; wave = 32 tok x 32 f (gate+up).
// LDS buffer: X 8K | G 8K | U 8K = 24KB fp32; double-buffered = 48KB -> 3 blocks/CU.
// per wave per step: 6 gll16 -> s_waitcnt vmcnt(6) (counted, never 0 mid-loop).
#define GU_XO 0
#define GU_GO 8192
#define GU_UO 16384
#define GU_STRIDE 24576
#define GU_NST 64

__global__ __launch_bounds__(256, 3) void gateup_mfma(
    const float* __restrict__ x,
    const float* __restrict__ w_gate, const float* __restrict__ w_up,
    const int* __restrict__ count, const int* __restrict__ offsets,
    const int* __restrict__ list_token, const float* __restrict__ list_w,
    unsigned short* __restrict__ h)
{
    const int e  = blockIdx.z;
    const int n  = count[e];
    const int m0 = blockIdx.y * 64;
    if (m0 >= n) return;
    const int f0 = blockIdx.x * 64;
    const int mc = min(64, n - m0);

    __shared__ char  lds[2 * GU_STRIDE];
    __shared__ int   toks[64];
    __shared__ float rws[64];

    const int tid = threadIdx.x;
    if (tid < 64) {
        const int idx = e * BS + m0 + (tid < mc ? tid : 0);
        toks[tid] = list_token[idx];
        rws[tid]  = (tid < mc) ? list_w[idx] : 0.f;
    }
    __syncthreads();

    const int lane = tid & 63, wave = tid >> 6;
    const int wr = wave >> 1, wc = wave & 1;
    const int q  = lane & 7;      // 16B block within 128B row
    const int r8 = lane >> 3;     // row within 8-row chunk

    // per-lane global sources (source-swizzled column block), stepped by +32 floats
    const float* xsrc[2];
    const float* gsrc[2];
    const float* usrc[2];
    #pragma unroll
    for (int i = 0; i < 2; ++i) {
        const int row = wave * 16 + i * 8 + r8;
        const int cs  = (q ^ (row & 7)) << 2;
        xsrc[i] = x + (size_t)toks[row] * DIM + cs;
        gsrc[i] = w_gate + (size_t)e * NF * DIM + (size_t)(f0 + row) * DIM + cs;
        usrc[i] = w_up   + (size_t)e * NF * DIM + (size_t)(f0 + row) * DIM + cs;
    }

    f32x4 accg[2][2] = {};
    f32x4 accu[2][2] = {};
    const int cb0 = (lane >> 4) * 2;
    const int ldd = wave * 2048;   // wave-uniform LDS chunk base

    // prologue: stage step 0 into buf 0
    #pragma unroll
    for (int i = 0; i < 2; ++i) {
        gll16(xsrc[i], &lds[GU_XO + ldd + i * 1024]);
        gll16(gsrc[i], &lds[GU_GO + ldd + i * 1024]);
        gll16(usrc[i], &lds[GU_UO + ldd + i * 1024]);
    }

    for (int t = 0; t < GU_NST; ++t) {
        const char* buf = &lds[(t & 1) * GU_STRIDE];
        if (t + 1 < GU_NST) {
            const int nb = ((t + 1) & 1) * GU_STRIDE;
            const int ko = (t + 1) * 32;
            #pragma unroll
            for (int i = 0; i < 2; ++i) {
                gll16(xsrc[i] + ko, &lds[nb + GU_XO + ldd + i * 1024]);
                gll16(gsrc[i] + ko, &lds[nb + GU_GO + ldd + i * 1024]);
                gll16(usrc[i] + ko, &lds[nb + GU_UO + ldd + i * 1024]);
            }
            asm volatile("s_waitcnt vmcnt(6)" ::: "memory");   // step-t data landed
        } else {
            asm volatile("s_waitcnt vmcnt(0)" ::: "memory");
        }
        __builtin_amdgcn_s_barrier();
        __builtin_amdgcn_sched_barrier(0);

        bf16x8 a[2], bg[2], bu[2];
        #pragma unroll
        for (int m = 0; m < 2; ++m)
            a[m] = fragf32(buf + GU_XO, wr * 32 + m * 16 + (lane & 15), cb0);
        #pragma unroll
        for (int nn = 0; nn < 2; ++nn) {
            const int r = wc * 32 + nn * 16 + (lane & 15);
            bg[nn] = fragf32(buf + GU_GO, r, cb0);
            bu[nn] = fragf32(buf + GU_UO, r, cb0);
        }
        #pragma unroll
        for (int m = 0; m < 2; ++m)
            #pragma unroll
            for (int nn = 0; nn < 2; ++nn) {
                accg[m][nn] = __builtin_amdgcn_mfma_f32_16x16x32_bf16(a[m], bg[nn], accg[m][nn], 0, 0, 0);
                accu[m][nn] = __builtin_amdgcn_mfma_f32_16x16x32_bf16(a[m], bu[nn], accu[m][nn], 0, 0, 0);
            }
        __builtin_amdgcn_sched_barrier(0);
        __builtin_amdgcn_s_barrier();    // buf[t&1] free for t+2's gll
    }

    const int base = offsets[e] + m0;
    #pragma unroll
    for (int m = 0; m < 2; ++m) {
        #pragma unroll
        for (int j = 0; j < 4; ++j) {
            const int tl = wr * 32 + m * 16 + (lane >> 4) * 4 + j;
            if (tl < mc) {
                const float w = rws[tl];
                #pragma unroll
                for (int nn = 0; nn < 2; ++nn) {
                    const int fl = f0 + wc * 32 + nn * 16 + (lane & 15);
                    const float g  = accg[m][nn][j];
                    const float u  = accu[m][nn][j];
                    const float hv = w * u * (g / (1.f + __expf(-g)));
                    h[(size_t)(base + tl) * NF + fl] = f2bf(hv);
                }
            }
        }
    }
}

// ---------------- down MFMA GEMM: async gll pipeline, BK=32 over F, 16 steps ----------------
// block: 64 slots x 128 d. 4 waves; wave = 32 x 64.
// LDS buffer: H 4K (bf16) | W 16K (fp32) = 20KB; dbuf 40KB -> 3 blocks/CU.
// per wave per step: 5 gll16 -> s_waitcnt vmcnt(5).
#define DK_HO 0
#define DK_WO 4096
#define DK_STRIDE 20480
#define DK_NST 16

__global__ __launch_bounds__(256, 3) void down_mfma(
    const float* __restrict__ w_down,
    const int* __restrict__ count, const int* __restrict__ offsets,
    const int* __restrict__ list_token,
    const unsigned short* __restrict__ h, float* __restrict__ out)
{
    const int e  = blockIdx.z;
    const int n  = count[e];
    const int m0 = blockIdx.y * 64;
    if (m0 >= n) return;
    const int d0 = blockIdx.x * 128;
    const int mc = min(64, n - m0);

    __shared__ char lds[2 * DK_STRIDE];
    __shared__ int  toks[64];

    const int tid = threadIdx.x;
    if (tid < 64) toks[tid] = list_token[e * BS + m0 + (tid < mc ? tid : 0)];
    __syncthreads();

    const int lane = tid & 63, wave = tid >> 6;
    const int wr = wave >> 1, wc = wave & 1;
    const int q  = lane & 7,  r8 = lane >> 3;
    const int q4 = lane & 3,  r4 = lane >> 2;

    const float* wd  = w_down + (size_t)e * DIM * NF;
    const int   base = offsets[e] + m0;

    // H: one gll per wave: rows wave*16 + r4 (64B rows, 4 blocks, swz (row>>1)&3)
    const int hrow = wave * 16 + r4;
    const unsigned short* hsrc =
        h + (size_t)(base + (hrow < mc ? hrow : 0)) * NF + ((q4 ^ ((hrow >> 1) & 3)) << 3);
    // W: 4 gll per wave: rows wave*32 + i*8 + r8 (128B rows, swz row&7)
    const float* wsrc[4];
    #pragma unroll
    for (int i = 0; i < 4; ++i) {
        const int row = wave * 32 + i * 8 + r8;
        wsrc[i] = wd + (size_t)(d0 + row) * NF + ((q ^ (row & 7)) << 2);
    }

    f32x4 acc[2][4] = {};
    const int cb0 = (lane >> 4) * 2;
    const int cbh = lane >> 4;

    // prologue
    gll16(hsrc, &lds[DK_HO + wave * 1024]);
    #pragma unroll
    for (int i = 0; i < 4; ++i)
        gll16(wsrc[i], &lds[DK_WO + wave * 4096 + i * 1024]);

    for (int t = 0; t < DK_NST; ++t) {
        const char* buf = &lds[(t & 1) * DK_STRIDE];
        if (t + 1 < DK_NST) {
            const int nb = ((t + 1) & 1) * DK_STRIDE;
            const int fo = (t + 1) * 32;
            gll16(hsrc + fo, &lds[nb + DK_HO + wave * 1024]);
            #pragma unroll
            for (int i = 0; i < 4; ++i)
                gll16(wsrc[i] + fo, &lds[nb + DK_WO + wave * 4096 + i * 1024]);
            asm volatile("s_waitcnt vmcnt(5)" ::: "memory");
        } else {
            asm volatile("s_waitcnt vmcnt(0)" ::: "memory");
        }
        __builtin_amdgcn_s_barrier();
        __builtin_amdgcn_sched_barrier(0);

        bf16x8 a[2], b[4];
        #pragma unroll
        for (int m = 0; m < 2; ++m)
            a[m] = fragbf16(buf + DK_HO, wr * 32 + m * 16 + (lane & 15), cbh);
        #pragma unroll
        for (int nn = 0; nn < 4; ++nn)
            b[nn] = fragf32(buf + DK_WO, wc * 64 + nn * 16 + (lane & 15), cb0);
        #pragma unroll
        for (int m = 0; m < 2; ++m)
            #pragma unroll
            for (int nn = 0; nn < 4; ++nn)
                acc[m][nn] = __builtin_amdgcn_mfma_f32_16x16x32_bf16(a[m], b[nn], acc[m][nn], 0, 0, 0);
        __builtin_amdgcn_sched_barrier(0);
        __builtin_amdgcn_s_barrier();
    }

    #pragma unroll
    for (int m = 0; m < 2; ++m)
        #pragma unroll
        for (int j = 0; j < 4; ++j) {
            const int sl = wr * 32 + m * 16 + (lane >> 4) * 4 + j;
            if (sl < mc) {
                float* orow = out + (size_t)toks[sl] * DIM + d0 + wc * 64 + (lane & 15);
                #pragma unroll
                for (int nn = 0; nn < 4; ++nn)
                    atomicAdd(&orow[nn * 16], acc[m][nn][j]);
            }
        }
}

extern "C" void kernel_launch(void* const* d_in, const int* in_sizes, int n_in,
                              void* d_out, int out_size, void* d_ws, size_t ws_size,
                              hipStream_t stream)
{
    const float* x          = (const float*)d_in[0];
    const float* gate_w     = (const float*)d_in[1];
    const float* w_gate     = (const float*)d_in[2];
    const float* w_up       = (const float*)d_in[3];
    const float* w_down     = (const float*)d_in[4];
    const int*   token_mod  = (const int*)d_in[5];
    const int*   expert_mod = (const int*)d_in[6];
    float* out = (float*)d_out;

    // ws layout: h bf16 (16384*512*2 = 16,777,216 B) | count | offsets | list_token | list_w
    char* ws = (char*)d_ws;
    unsigned short* h  = (unsigned short*)ws;
    int*   count      = (int*)(ws + 16777216);
    int*   offsets    = (int*)(ws + 16777216 + 256);
    int*   list_token = (int*)(ws + 16777216 + 512);
    float* list_w     = (float*)(ws + 16777216 + 512 + (size_t)NE * BS * 4);

    zero_kernel<<<2048, 256, 0, stream>>>(out, count);
    router_kernel<<<BS / 4, 256, 0, stream>>>(x, gate_w, token_mod, expert_mod,
                                              count, list_token, list_w);
    scan_kernel<<<1, 64, 0, stream>>>(count, offsets);

    dim3 g1(NF / 64, BS / 64, NE);     // (8, 32, 64)
    gateup_mfma<<<g1, 256, 0, stream>>>(x, w_gate, w_up, count, offsets,
                                        list_token, list_w, h);
    dim3 g2(DIM / 128, BS / 64, NE);   // (16, 32, 64)
    down_mfma<<<g2, 256, 0, stream>>>(w_down, count, offsets, list_token, h, out);
}